// Round 1
// baseline (77.477 us; speedup 1.0000x reference)
//
#include <hip/hip_runtime.h>

// B-spline (piecewise-linear) activation, NCHW fp32.
// N=64, C=256, H=W=56, SIZE=51 knots per channel, GRID=0.1.
// One block per (n,c) plane: channel is block-uniform, only 51 coeffs
// needed per block -> 204 B LDS, float4 streaming for x/out.

constexpr int C_CH   = 256;
constexpr int KSIZE  = 51;
constexpr int HW     = 56 * 56;   // 3136
constexpr int HW4    = HW / 4;    // 784

__global__ __launch_bounds__(256)
void bspline_act_kernel(const float* __restrict__ x,
                        const float* __restrict__ coeff,
                        const int*   __restrict__ zk,
                        float*       __restrict__ out)
{
    const int p   = blockIdx.x;          // plane index in [0, N*C)
    const int c   = p & (C_CH - 1);      // channel (C_CH is power of two)
    const int tid = threadIdx.x;

    __shared__ float sc[KSIZE];
    if (tid < KSIZE) sc[tid] = coeff[c * KSIZE + tid];
    // bias maps (int)floor -> local LDS index; == half_knots (25) per setup,
    // but honor the zero_knot_indexes input.
    const int bias = zk[c] - c * KSIZE;
    __syncthreads();

    const float4* __restrict__ xv = (const float4*)(x + (size_t)p * HW);
    float4*       __restrict__ ov = (float4*)(out + (size_t)p * HW);

    for (int i = tid; i < HW4; i += 256) {
        float4 v = xv[i];
        float in4[4] = {v.x, v.y, v.z, v.w};
        float r4[4];
        #pragma unroll
        for (int k = 0; k < 4; ++k) {
            float xe = in4[k];
            // clamp bounds: float32(-0.1*25) = -2.5f, float32(0.1*24) = 2.4f
            float xc = fminf(fmaxf(xe, -2.5f), 2.4f);
            float fl = floorf(xc * 10.0f);       // left-knot offset
            float fr = xe * 10.0f - fl;          // frac uses UNclamped x
            int   li = (int)fl + bias;           // 0..49
            float c0 = sc[li];
            float c1 = sc[li + 1];
            r4[k] = c1 * fr + c0 * (1.0f - fr);
        }
        float4 r;
        r.x = r4[0]; r.y = r4[1]; r.z = r4[2]; r.w = r4[3];
        ov[i] = r;
    }
}

extern "C" void kernel_launch(void* const* d_in, const int* in_sizes, int n_in,
                              void* d_out, int out_size, void* d_ws, size_t ws_size,
                              hipStream_t stream) {
    const float* x     = (const float*)d_in[0];
    const float* coeff = (const float*)d_in[1];
    const int*   zk    = (const int*)d_in[2];
    float*       out   = (float*)d_out;

    const int n_planes = out_size / HW;  // N*C = 16384
    bspline_act_kernel<<<n_planes, 256, 0, stream>>>(x, coeff, zk, out);
}

// Round 3
// 68.904 us; speedup vs baseline: 1.1244x; 1.1244x over previous
//
#include <hip/hip_runtime.h>

// B-spline (piecewise-linear) activation, NCHW fp32.
// N=64, C=256, H=W=56, SIZE=51 knots per channel, GRID=0.1.
// One block per (n,c) plane; channel is block-uniform.
// LDS holds the 50 (c[i], c[i+1]) pairs -> single ds_read_b64 per element.
// All global loads issued up-front (3 full + predicated tail) for MLP;
// nontemporal loads/stores since neither stream has reuse.
// Native clang vector type: __builtin_nontemporal_* rejects HIP_vector_type.

typedef float f32x4 __attribute__((ext_vector_type(4)));

constexpr int C_CH  = 256;
constexpr int KSIZE = 51;
constexpr int HW    = 56 * 56;   // 3136
constexpr int HW4   = HW / 4;    // 784 float4 per plane (= 3*256 + 16)

__device__ __forceinline__ f32x4 bspline4(f32x4 v, const float2* sc, int bias) {
    f32x4 r;
    #pragma unroll
    for (int k = 0; k < 4; ++k) {
        float xe = v[k];
        // float32(-0.1*25) = -2.5f, float32(0.1*24) = 2.4f
        float xc = fminf(fmaxf(xe, -2.5f), 2.4f);
        float fl = floorf(xc * 10.0f);        // left-knot offset
        float fr = xe * 10.0f - fl;           // frac uses UNclamped x
        float2 cc = sc[(int)fl + bias];       // (c0, c1), one ds_read_b64
        r[k] = cc.y * fr + cc.x * (1.0f - fr);
    }
    return r;
}

__global__ __launch_bounds__(256)
void bspline_act_kernel(const float* __restrict__ x,
                        const float* __restrict__ coeff,
                        const int*   __restrict__ zk,
                        float*       __restrict__ out)
{
    const int p   = blockIdx.x;          // plane index in [0, N*C)
    const int c   = p & (C_CH - 1);      // channel (C_CH is power of two)
    const int tid = threadIdx.x;

    __shared__ float2 sc[KSIZE - 1];     // sc[i] = (coeff[i], coeff[i+1])
    if (tid < KSIZE - 1) {
        float a = coeff[c * KSIZE + tid];
        float b = coeff[c * KSIZE + tid + 1];
        sc[tid] = make_float2(a, b);
    }
    const int bias = zk[c] - c * KSIZE;  // == half_knots (25)
    __syncthreads();

    const f32x4* __restrict__ xv = (const f32x4*)(x + (size_t)p * HW);
    f32x4*       __restrict__ ov = (f32x4*)(out + (size_t)p * HW);

    // Issue all loads before any dependent compute: 3-4 in flight per thread.
    f32x4 v0 = __builtin_nontemporal_load(&xv[tid]);
    f32x4 v1 = __builtin_nontemporal_load(&xv[tid + 256]);
    f32x4 v2 = __builtin_nontemporal_load(&xv[tid + 512]);
    const bool tail = tid < (HW4 - 768); // 16 float4 tail
    f32x4 v3;
    if (tail) v3 = __builtin_nontemporal_load(&xv[tid + 768]);

    f32x4 r0 = bspline4(v0, sc, bias);
    f32x4 r1 = bspline4(v1, sc, bias);
    f32x4 r2 = bspline4(v2, sc, bias);
    __builtin_nontemporal_store(r0, &ov[tid]);
    __builtin_nontemporal_store(r1, &ov[tid + 256]);
    __builtin_nontemporal_store(r2, &ov[tid + 512]);
    if (tail) {
        f32x4 r3 = bspline4(v3, sc, bias);
        __builtin_nontemporal_store(r3, &ov[tid + 768]);
    }
}

extern "C" void kernel_launch(void* const* d_in, const int* in_sizes, int n_in,
                              void* d_out, int out_size, void* d_ws, size_t ws_size,
                              hipStream_t stream) {
    const float* x     = (const float*)d_in[0];
    const float* coeff = (const float*)d_in[1];
    const int*   zk    = (const int*)d_in[2];
    float*       out   = (float*)d_out;

    const int n_planes = out_size / HW;  // N*C = 16384
    bspline_act_kernel<<<n_planes, 256, 0, stream>>>(x, coeff, zk, out);
}